// Round 4
// baseline (189.241 us; speedup 1.0000x reference)
//
#include <hip/hip_runtime.h>

// MaskedQueryAndGroup — masked ordered ball query + grouping.
// Shapes: B=4, NPOINT=2048, N=8192, C=64, NSAMPLE=32, R=0.1.
//
// Evidence log:
//  R1 (fp32, no-fma dot, int32 masks): absmax 4.703125 (== ~max|features|),
//     no NaN -> layout/dtypes right, a few wrong indices.
//  R2 (bf16 experiment): NaN -> dataset is definitively fp32.
//  R3 (mask width probe): identical 4.703125 -> masks were never the bug.
//  R4 theory: d2 boundary flips. d2 = (|q|^2+|s|^2) - 2 q.s cancels ~1.5 down
//     to ~0.01; 1-ulp dot difference perturbs d2 by ~1.2e-7; ~3 expected
//     membership flips over 54M pairs -> slot shifts -> error ~max|f|.
//     Reference einsum lowers to GEMM (Eigen/OpenBLAS), K=3 inner product is
//     an FMA chain: acc=q0*s0; acc=fma(q1,s1,acc); acc=fma(q2,s2,acc).
//     |q|^2 / |s|^2 are elementwise mul + sequential reduce (no fma).
//     This round: dot via explicit fma chain; qq/ss plain; contract off.

#define NPOINT 2048
#define NSUP   8192
#define NCH    64
#define NS     32

__global__ __launch_bounds__(256) void mqag_kernel(
    const float* __restrict__ query_xyz,    // (B,3,NPOINT) f32
    const float* __restrict__ support_xyz,  // (B,3,N)      f32
    const void*  __restrict__ query_mask_raw,   // (B,NPOINT)  bool8 or int32
    const void*  __restrict__ support_mask_raw, // (B,N)       bool8 or int32
    const float* __restrict__ features,     // (B,C,N)      f32
    float* __restrict__ out,                // f32: (B,67,NPOINT,NS) ++ (B,NPOINT,NS)
    int B)
{
#pragma clang fp contract(off)
    const int wib  = threadIdx.x >> 6;           // wave in block (0..3)
    const int lane = threadIdx.x & 63;
    const int qid  = blockIdx.x * 4 + wib;       // one wave per query
    const int b    = qid / NPOINT;
    const int p    = qid % NPOINT;

    __shared__ int slots_all[4][NS];
    int* slots = slots_all[wib];

    // Mask element-width probe (wave-uniform): int32/f32 masks have byte
    // 4i+1 == 0 always; byte bools ~90% nonzero there (false-detect 0.1^64).
    const unsigned char* smb = (const unsigned char*)support_mask_raw;
    const bool mask_is_4byte = (__ballot(smb[4 * lane + 1] != 0) == 0ull);
    const unsigned char* qmb = (const unsigned char*)query_mask_raw;
    const int* smi = (const int*)support_mask_raw;
    const int* qmi = (const int*)query_mask_raw;

    const float* sx = support_xyz + (size_t)b * 3 * NSUP;
    const float* sy = sx + NSUP;
    const float* sz = sx + 2 * NSUP;

    const float qx = query_xyz[(size_t)b * 3 * NPOINT + p];
    const float qy = query_xyz[(size_t)b * 3 * NPOINT + NPOINT + p];
    const float qz = query_xyz[(size_t)b * 3 * NPOINT + 2 * NPOINT + p];
    const bool  qm = mask_is_4byte ? (qmi[b * NPOINT + p] != 0)
                                   : (qmb[b * NPOINT + p] != 0);

    // |q|^2: elementwise mul + sequential reduce, NO fma (matches XLA/np).
    const float qq = (qx * qx + qy * qy) + qz * qz;

    int cnt = 0;
    if (qm) {
        for (int base = 0; base < NSUP; base += 64) {
            const int n = base + lane;
            const float x = sx[n];
            const float y = sy[n];
            const float z = sz[n];
            const bool  m = mask_is_4byte ? (smi[b * NSUP + n] != 0)
                                          : (smb[b * NSUP + n] != 0);
            const float ss = (x * x + y * y) + z * z;       // no fma
            // dot: GEMM K=3 FMA chain (Eigen/OpenBLAS inner product).
            const float dot = __builtin_fmaf(qz, z,
                              __builtin_fmaf(qy, y, qx * x));
            const float d2  = (qq + ss) - 2.0f * dot;        // 2*dot exact
            const bool within = (d2 <= 0.01f) && m;
            const unsigned long long bal = __ballot(within);
            if (within) {
                const int r = cnt + __popcll(bal & ((1ull << lane) - 1ull));
                if (r < NS) slots[r] = n;
            }
            cnt += __popcll(bal);                            // wave-uniform
            if (cnt >= NS) break;                            // uniform break
        }
    }
    const int found = cnt < NS ? cnt : NS;

    __syncthreads();

    // Pad unfilled slots with first neighbor (0 if none) — matches top_k pad.
    const int first = (found > 0) ? slots[0] : 0;
    if (lane < NS && lane >= found) slots[lane] = first;

    __syncthreads();

    // idx_mask output (f32 0/1), appended after new_features.
    const size_t nf_elems = (size_t)B * 67 * NPOINT * NS;
    if (lane < NS) {
        out[nf_elems + ((size_t)b * NPOINT + p) * NS + lane] =
            (lane < found) ? 1.0f : 0.0f;
    }

    // Gather: 67 channels x 32 slots = 2144 f32 per query.
    const float* feat = features + (size_t)b * NCH * NSUP;
    for (int i = 0; i < (67 * NS + 63) / 64; ++i) {
        const int flat = i * 64 + lane;
        if (flat < 67 * NS) {
            const int ch = flat >> 5;
            const int k  = flat & 31;
            const int idx = slots[k];
            float val;
            if (ch < 3) {
                const float s = sx[(size_t)ch * NSUP + idx];
                const float q = (ch == 0) ? qx : ((ch == 1) ? qy : qz);
                val = (s - q) / 0.1f;   // normalize_xyz, division like the ref
            } else {
                val = feat[(size_t)(ch - 3) * NSUP + idx];
            }
            out[(((size_t)b * 67 + ch) * NPOINT + p) * NS + k] = val;
        }
    }
}

extern "C" void kernel_launch(void* const* d_in, const int* in_sizes, int n_in,
                              void* d_out, int out_size, void* d_ws, size_t ws_size,
                              hipStream_t stream) {
    const float* query_xyz    = (const float*)d_in[0];
    const float* support_xyz  = (const float*)d_in[1];
    const void*  query_mask   = d_in[2];
    const void*  support_mask = d_in[3];
    const float* features     = (const float*)d_in[4];

    const int B = in_sizes[0] / (3 * NPOINT);      // = 4
    const int total_queries = B * NPOINT;          // 8192
    const dim3 grid(total_queries / 4);            // 4 waves (queries) per block
    const dim3 block(256);

    hipLaunchKernelGGL(mqag_kernel, grid, block, 0, stream,
                       query_xyz, support_xyz, query_mask, support_mask,
                       features, (float*)d_out, B);
}

// Round 6
// 159.544 us; speedup vs baseline: 1.1861x; 1.1861x over previous
//
#include <hip/hip_runtime.h>

// MaskedQueryAndGroup — masked ordered ball query + grouping.
// Shapes: B=4, NPOINT=2048, N=8192, C=64, NSAMPLE=32, R=0.1.
//
// Evidence log:
//  R1-R3: fp32 dataset; masks readable as int32; out = new_features
//    (B,67,NPOINT,32) ++ idx_mask (B,NPOINT,32), both f32.
//  R4 PASSED absmax 0.0, 131 us: dot = fma(qz,z,fma(qy,y,qx*x)), ss/qq plain
//    mul+add, d2=(qq+ss)-2*dot, contract off. DO NOT change d2 arithmetic.
//  R5 FAILED absmax 9.92 (~|s-q|/0.1 for wrong/missing neighbor): grid path
//    lost candidates. Suspect: shfl_up prefix + dynamic-shfl binary-search
//    load balancer (most exotic block; sort & scan hand-verified).
//  R6: same grid, same build_grid, same bitonic sort; candidate enumeration
//    replaced by wave-uniform loop over contiguous x-run ranges (cells with
//    consecutive x are consecutive ids -> contiguous pts ranges; <=16 ranges).
//    Plus per-candidate support_mask recheck (armor). If R6 fails same way,
//    bug is in build_grid or sort.

#define NPOINT 2048
#define NSUP   8192
#define NCH    64
#define NS     32
#define GRID1  10
#define CELLS  1000   // 10*10*10

// ---------- helpers ----------
__device__ __forceinline__ bool probe_mask4(const void* mask) {
    // int32/f32 masks have byte 4i+1 == 0 always; byte bools ~90% nonzero.
    const unsigned char* mb = (const unsigned char*)mask;
    const int lane = threadIdx.x & 63;
    return __ballot(mb[4 * lane + 1] != 0) == 0ull;
}
__device__ __forceinline__ bool read_mask(const void* mask, int i, bool is4) {
    return is4 ? (((const int*)mask)[i] != 0)
               : (((const unsigned char*)mask)[i] != 0);
}

// ---------- grid build: one block per batch (byte-identical to R5) ----------
__global__ __launch_bounds__(1024) void build_grid(
    const float* __restrict__ support_xyz,   // (B,3,N)
    const void*  __restrict__ support_mask,  // (B,N)
    float4* __restrict__ pts,                // (B,N) packed (x,y,z,idx-bits)
    int* __restrict__ starts)                // (B,CELLS+1) exclusive offsets
{
    __shared__ unsigned short cell_s[NSUP];  // 16KB
    __shared__ int cnts[CELLS];              // 4KB
    __shared__ int scanb[1024];              // 4KB
    __shared__ int offs[CELLS + 1];          // 4KB
    const int tid = threadIdx.x;
    const int b   = blockIdx.x;
    const bool m4 = probe_mask4(support_mask);

    const float* sx = support_xyz + (size_t)b * 3 * NSUP;
    const float* sy = sx + NSUP;
    const float* sz = sx + 2 * NSUP;

    for (int i = tid; i < CELLS; i += 1024) cnts[i] = 0;
    __syncthreads();

    for (int n = tid; n < NSUP; n += 1024) {
        int cid = 0xFFFF;
        if (read_mask(support_mask, b * NSUP + n, m4)) {
            const int cx = min(GRID1 - 1, (int)(sx[n] * 10.0f));
            const int cy = min(GRID1 - 1, (int)(sy[n] * 10.0f));
            const int cz = min(GRID1 - 1, (int)(sz[n] * 10.0f));
            cid = cx + GRID1 * cy + GRID1 * GRID1 * cz;
            atomicAdd(&cnts[cid], 1);
        }
        cell_s[n] = (unsigned short)cid;
    }
    __syncthreads();

    scanb[tid] = (tid < CELLS) ? cnts[tid] : 0;
    __syncthreads();
    for (int d = 1; d < 1024; d <<= 1) {
        int v = 0;
        if (tid >= d) v = scanb[tid - d];
        __syncthreads();
        if (tid >= d) scanb[tid] += v;
        __syncthreads();
    }
    if (tid == 0) offs[0] = 0;
    if (tid < CELLS) offs[tid + 1] = scanb[tid];
    __syncthreads();
    for (int i = tid; i <= CELLS; i += 1024) starts[b * (CELLS + 1) + i] = offs[i];
    for (int i = tid; i < CELLS; i += 1024) cnts[i] = 0;  // reuse as cursors
    __syncthreads();

    for (int n = tid; n < NSUP; n += 1024) {
        const int cid = cell_s[n];
        if (cid != 0xFFFF) {
            const int pos = offs[cid] + atomicAdd(&cnts[cid], 1);
            pts[(size_t)b * NSUP + pos] =
                make_float4(sx[n], sy[n], sz[n], __int_as_float(n));
        }
    }
}

// ---------- main: grid query via contiguous x-run ranges ----------
__global__ __launch_bounds__(256) void mqag_grid(
    const float* __restrict__ query_xyz, const float* __restrict__ support_xyz,
    const void* __restrict__ query_mask, const void* __restrict__ support_mask,
    const float* __restrict__ features,
    const float4* __restrict__ pts, const int* __restrict__ starts,
    float* __restrict__ out, int B)
{
#pragma clang fp contract(off)
    const int wib  = threadIdx.x >> 6;
    const int lane = threadIdx.x & 63;
    const int qid  = blockIdx.x * 4 + wib;
    const int b    = qid / NPOINT;
    const int p    = qid % NPOINT;

    __shared__ int hits_all[4][64];
    __shared__ int slots_all[4][NS];
    int* hits  = hits_all[wib];
    int* slots = slots_all[wib];

    const bool m4s = probe_mask4(support_mask);
    const bool m4q = probe_mask4(query_mask);

    const float* sx = support_xyz + (size_t)b * 3 * NSUP;
    const float* sy = sx + NSUP;
    const float* sz = sx + 2 * NSUP;

    const float qx = query_xyz[(size_t)b * 3 * NPOINT + p];
    const float qy = query_xyz[(size_t)b * 3 * NPOINT + NPOINT + p];
    const float qz = query_xyz[(size_t)b * 3 * NPOINT + 2 * NPOINT + p];
    const bool  qm = read_mask(query_mask, b * NPOINT + p, m4q);
    const float qq = (qx * qx + qy * qy) + qz * qz;   // no fma (matches ref)

    int cnt = 0;
    if (qm) {
        const int x0 = max(0, (int)floorf((qx - 0.101f) * 10.f));
        const int x1 = min(GRID1 - 1, (int)floorf((qx + 0.101f) * 10.f));
        const int y0 = max(0, (int)floorf((qy - 0.101f) * 10.f));
        const int y1 = min(GRID1 - 1, (int)floorf((qy + 0.101f) * 10.f));
        const int z0 = max(0, (int)floorf((qz - 0.101f) * 10.f));
        const int z1 = min(GRID1 - 1, (int)floorf((qz + 0.101f) * 10.f));
        const int ncx = x1 - x0 + 1;

        const int*    stb  = starts + b * (CELLS + 1);
        const float4* ptsb = pts + (size_t)b * NSUP;

        // Cells with consecutive x at fixed (y,z) are consecutive ids ->
        // contiguous pts range [starts[c0], starts[c0+ncx]).
        for (int cz = z0; cz <= z1; ++cz) {
            for (int cy = y0; cy <= y1; ++cy) {
                const int c0 = x0 + GRID1 * cy + GRID1 * GRID1 * cz;
                const int s0 = stb[c0];
                const int e0 = stb[c0 + ncx];
                for (int tb = s0; tb < e0; tb += 64) {
                    const int g  = tb + lane;
                    const bool valid = g < e0;
                    const float4 pv = ptsb[valid ? g : (e0 - 1)];
                    const int nidx = __float_as_int(pv.w);
                    // EXACT R4 membership arithmetic (bit-exact vs ref):
                    const float ss  = (pv.x * pv.x + pv.y * pv.y) + pv.z * pv.z;
                    const float dot = __builtin_fmaf(qz, pv.z,
                                      __builtin_fmaf(qy, pv.y, qx * pv.x));
                    const float d2  = (qq + ss) - 2.0f * dot;
                    const bool within = valid && (d2 <= 0.01f)
                        && read_mask(support_mask, b * NSUP + nidx, m4s);
                    const unsigned long long bal = __ballot(within);
                    if (within) {
                        const int r = cnt + __popcll(bal & ((1ull << lane) - 1ull));
                        if (r < 64) hits[r] = nidx;
                    }
                    cnt += __popcll(bal);
                }
            }
        }
    }

    __syncthreads();   // hits visible; convergent for all waves

    if (cnt > 64) {
        // rare overflow: exact ordered linear rescan (R4 loop)
        int c2 = 0;
        for (int basei = 0; basei < NSUP; basei += 64) {
            const int n = basei + lane;
            const float x = sx[n], y = sy[n], z = sz[n];
            const bool  m = read_mask(support_mask, b * NSUP + n, m4s);
            const float ss  = (x * x + y * y) + z * z;
            const float dot = __builtin_fmaf(qz, z,
                              __builtin_fmaf(qy, y, qx * x));
            const float d2  = (qq + ss) - 2.0f * dot;
            const bool within = (d2 <= 0.01f) && m;
            const unsigned long long bal = __ballot(within);
            if (within) {
                const int r = c2 + __popcll(bal & ((1ull << lane) - 1ull));
                if (r < NS) slots[r] = n;
            }
            c2 += __popcll(bal);
            if (c2 >= NS) break;
        }
        cnt = c2;
    } else {
        // bitonic sort 64 lanes ascending (hand-verified); empties = INT_MAX
        int v = (lane < cnt) ? hits[lane] : 0x7FFFFFFF;
        #pragma unroll
        for (int k = 2; k <= 64; k <<= 1) {
            #pragma unroll
            for (int j = k >> 1; j > 0; j >>= 1) {
                const int pv = __shfl_xor(v, j, 64);
                const bool keep_min = ((lane & j) == 0) == ((lane & k) == 0);
                const int mn = min(v, pv), mx = max(v, pv);
                v = keep_min ? mn : mx;
            }
        }
        if (lane < NS && lane < cnt) slots[lane] = v;
    }
    const int found = (cnt < NS) ? cnt : NS;

    __syncthreads();
    const int first = (found > 0) ? slots[0] : 0;
    if (lane < NS && lane >= found) slots[lane] = first;
    __syncthreads();

    const size_t nf_elems = (size_t)B * 67 * NPOINT * NS;
    if (lane < NS) {
        out[nf_elems + ((size_t)b * NPOINT + p) * NS + lane] =
            (lane < found) ? 1.0f : 0.0f;
    }

    const float* feat = features + (size_t)b * NCH * NSUP;
    for (int i = 0; i < (67 * NS + 63) / 64; ++i) {
        const int flat = i * 64 + lane;
        if (flat < 67 * NS) {
            const int ch = flat >> 5;
            const int k  = flat & 31;
            const int idx = slots[k];
            float val;
            if (ch < 3) {
                const float s = sx[(size_t)ch * NSUP + idx];
                const float q = (ch == 0) ? qx : ((ch == 1) ? qy : qz);
                val = (s - q) / 0.1f;
            } else {
                val = feat[(size_t)(ch - 3) * NSUP + idx];
            }
            out[(((size_t)b * 67 + ch) * NPOINT + p) * NS + k] = val;
        }
    }
}

// ---------- proven R4 linear kernel (fallback if ws too small) ----------
__global__ __launch_bounds__(256) void mqag_linear(
    const float* __restrict__ query_xyz, const float* __restrict__ support_xyz,
    const void* __restrict__ query_mask_raw, const void* __restrict__ support_mask_raw,
    const float* __restrict__ features, float* __restrict__ out, int B)
{
#pragma clang fp contract(off)
    const int wib  = threadIdx.x >> 6;
    const int lane = threadIdx.x & 63;
    const int qid  = blockIdx.x * 4 + wib;
    const int b    = qid / NPOINT;
    const int p    = qid % NPOINT;

    __shared__ int slots_all[4][NS];
    int* slots = slots_all[wib];

    const bool m4s = probe_mask4(support_mask_raw);
    const bool m4q = probe_mask4(query_mask_raw);

    const float* sx = support_xyz + (size_t)b * 3 * NSUP;
    const float* sy = sx + NSUP;
    const float* sz = sx + 2 * NSUP;

    const float qx = query_xyz[(size_t)b * 3 * NPOINT + p];
    const float qy = query_xyz[(size_t)b * 3 * NPOINT + NPOINT + p];
    const float qz = query_xyz[(size_t)b * 3 * NPOINT + 2 * NPOINT + p];
    const bool  qm = read_mask(query_mask_raw, b * NPOINT + p, m4q);
    const float qq = (qx * qx + qy * qy) + qz * qz;

    int cnt = 0;
    if (qm) {
        for (int base = 0; base < NSUP; base += 64) {
            const int n = base + lane;
            const float x = sx[n], y = sy[n], z = sz[n];
            const bool  m = read_mask(support_mask_raw, b * NSUP + n, m4s);
            const float ss  = (x * x + y * y) + z * z;
            const float dot = __builtin_fmaf(qz, z, __builtin_fmaf(qy, y, qx * x));
            const float d2  = (qq + ss) - 2.0f * dot;
            const bool within = (d2 <= 0.01f) && m;
            const unsigned long long bal = __ballot(within);
            if (within) {
                const int r = cnt + __popcll(bal & ((1ull << lane) - 1ull));
                if (r < NS) slots[r] = n;
            }
            cnt += __popcll(bal);
            if (cnt >= NS) break;
        }
    }
    const int found = cnt < NS ? cnt : NS;
    __syncthreads();
    const int first = (found > 0) ? slots[0] : 0;
    if (lane < NS && lane >= found) slots[lane] = first;
    __syncthreads();

    const size_t nf_elems = (size_t)B * 67 * NPOINT * NS;
    if (lane < NS) {
        out[nf_elems + ((size_t)b * NPOINT + p) * NS + lane] =
            (lane < found) ? 1.0f : 0.0f;
    }
    const float* feat = features + (size_t)b * NCH * NSUP;
    for (int i = 0; i < (67 * NS + 63) / 64; ++i) {
        const int flat = i * 64 + lane;
        if (flat < 67 * NS) {
            const int ch = flat >> 5;
            const int k  = flat & 31;
            const int idx = slots[k];
            float val;
            if (ch < 3) {
                const float s = sx[(size_t)ch * NSUP + idx];
                const float q = (ch == 0) ? qx : ((ch == 1) ? qy : qz);
                val = (s - q) / 0.1f;
            } else {
                val = feat[(size_t)(ch - 3) * NSUP + idx];
            }
            out[(((size_t)b * 67 + ch) * NPOINT + p) * NS + k] = val;
        }
    }
}

extern "C" void kernel_launch(void* const* d_in, const int* in_sizes, int n_in,
                              void* d_out, int out_size, void* d_ws, size_t ws_size,
                              hipStream_t stream) {
    const float* query_xyz    = (const float*)d_in[0];
    const float* support_xyz  = (const float*)d_in[1];
    const void*  query_mask   = d_in[2];
    const void*  support_mask = d_in[3];
    const float* features     = (const float*)d_in[4];

    const int B = in_sizes[0] / (3 * NPOINT);      // = 4
    const dim3 block(256);
    const dim3 grid(B * NPOINT / 4);               // 4 waves (queries) per block

    const size_t need = (size_t)B * NSUP * sizeof(float4)
                      + (size_t)B * (CELLS + 1) * sizeof(int);
    if (ws_size >= need) {
        float4* pts  = (float4*)d_ws;
        int* starts  = (int*)((char*)d_ws + (size_t)B * NSUP * sizeof(float4));
        hipLaunchKernelGGL(build_grid, dim3(B), dim3(1024), 0, stream,
                           support_xyz, support_mask, pts, starts);
        hipLaunchKernelGGL(mqag_grid, grid, block, 0, stream,
                           query_xyz, support_xyz, query_mask, support_mask,
                           features, pts, starts, (float*)d_out, B);
    } else {
        hipLaunchKernelGGL(mqag_linear, grid, block, 0, stream,
                           query_xyz, support_xyz, query_mask, support_mask,
                           features, (float*)d_out, B);
    }
}

// Round 7
// 129.120 us; speedup vs baseline: 1.4656x; 1.2356x over previous
//
#include <hip/hip_runtime.h>

// MaskedQueryAndGroup — masked ordered ball query + grouping.
// Shapes: B=4, NPOINT=2048, N=8192, C=64, NSAMPLE=32, R=0.1.
//
// Evidence log:
//  R1-R3: fp32 dataset; masks readable as int32; out = new_features
//    (B,67,NPOINT,32) ++ idx_mask (B,NPOINT,32), both f32.
//  R4 PASSED absmax 0.0, 131 us: dot = fma(qz,z,fma(qy,y,qx*x)), ss/qq plain
//    mul+add, d2=(qq+ss)-2*dot, contract off. DO NOT change d2 arithmetic.
//  R5 FAILED: shfl_up+binary-search load balancer lost candidates (localized
//    by R6 ablation). Avoid exotic cross-lane enumeration.
//  R6 PASSED absmax 0.0, 159.5 us total; mqag_grid 72 us, VALUBusy 15%,
//    HBM 18% -> LSU/latency-bound gather (half-wave scattered 4B reads,
//    ~64 cachelines/instr). build_grid ~30 us (4 blocks, serial scan).
//  R7: (a) features transposed to (N,C) in ws -> gather reads one neighbor's
//    64 ch as contiguous 256B (lane=ch), LDS 32x65 bounce (2-way conflicts =
//    free), channel-major coalesced stores unchanged. (b) build parallelized
//    into zero/hist/scan/fill kernels (scan block = R6-verified code).
//    Enumeration + bitonic sort + membership math byte-identical to R6.

#define NPOINT 2048
#define NSUP   8192
#define NCH    64
#define NS     32
#define GRID1  10
#define CELLS  1000   // 10*10*10

// ---------- helpers ----------
__device__ __forceinline__ bool probe_mask4(const void* mask) {
    // int32/f32 masks have byte 4i+1 == 0 always; byte bools ~90% nonzero.
    const unsigned char* mb = (const unsigned char*)mask;
    const int lane = threadIdx.x & 63;
    return __ballot(mb[4 * lane + 1] != 0) == 0ull;
}
__device__ __forceinline__ bool read_mask(const void* mask, int i, bool is4) {
    return is4 ? (((const int*)mask)[i] != 0)
               : (((const unsigned char*)mask)[i] != 0);
}
__device__ __forceinline__ int cell_of(float x, float y, float z) {
    const int cx = min(GRID1 - 1, (int)(x * 10.0f));
    const int cy = min(GRID1 - 1, (int)(y * 10.0f));
    const int cz = min(GRID1 - 1, (int)(z * 10.0f));
    return cx + GRID1 * cy + GRID1 * GRID1 * cz;
}

// ---------- build step 1: zero starts+cursors ----------
__global__ __launch_bounds__(256) void zero_ws(int* __restrict__ ptr, int n) {
    const int i = blockIdx.x * 256 + threadIdx.x;
    if (i < n) ptr[i] = 0;
}

// ---------- build step 2: histogram (counts at starts[b][cell+1]) ----------
__global__ __launch_bounds__(256) void grid_hist(
    const float* __restrict__ support_xyz, const void* __restrict__ support_mask,
    int* __restrict__ starts)
{
    const bool m4 = probe_mask4(support_mask);
    const int gid = blockIdx.x * 256 + threadIdx.x;   // grid sized B*NSUP exactly
    const int b = gid / NSUP, n = gid % NSUP;
    if (!read_mask(support_mask, gid, m4)) return;
    const float* sx = support_xyz + (size_t)b * 3 * NSUP;
    const int cid = cell_of(sx[n], sx[NSUP + n], sx[2 * NSUP + n]);
    atomicAdd(&starts[b * (CELLS + 1) + cid + 1], 1);
}

// ---------- build step 3: scan (R6-verified Hillis-Steele, standalone) ----------
__global__ __launch_bounds__(1024) void grid_scan(int* __restrict__ starts) {
    __shared__ int scanb[1024];
    const int tid = threadIdx.x;
    int* sb = starts + blockIdx.x * (CELLS + 1);
    scanb[tid] = (tid < CELLS) ? sb[tid + 1] : 0;
    __syncthreads();
    for (int d = 1; d < 1024; d <<= 1) {
        int v = 0;
        if (tid >= d) v = scanb[tid - d];
        __syncthreads();
        if (tid >= d) scanb[tid] += v;
        __syncthreads();
    }
    if (tid < CELLS) sb[tid + 1] = scanb[tid];   // sb[0] stays 0 (zero_ws)
}

// ---------- build step 4: fill pts ----------
__global__ __launch_bounds__(256) void grid_fill(
    const float* __restrict__ support_xyz, const void* __restrict__ support_mask,
    const int* __restrict__ starts, int* __restrict__ cursors,
    float4* __restrict__ pts)
{
    const bool m4 = probe_mask4(support_mask);
    const int gid = blockIdx.x * 256 + threadIdx.x;
    const int b = gid / NSUP, n = gid % NSUP;
    if (!read_mask(support_mask, gid, m4)) return;
    const float* sx = support_xyz + (size_t)b * 3 * NSUP;
    const float x = sx[n], y = sx[NSUP + n], z = sx[2 * NSUP + n];
    const int cid = cell_of(x, y, z);
    const int pos = starts[b * (CELLS + 1) + cid]
                  + atomicAdd(&cursors[b * CELLS + cid], 1);
    pts[(size_t)b * NSUP + pos] = make_float4(x, y, z, __int_as_float(n));
}

// ---------- features transpose: (B,C,N) -> (B,N,C) ----------
__global__ __launch_bounds__(256) void transpose_feat(
    const float* __restrict__ features, float* __restrict__ feat_t)
{
    __shared__ float tile[32][33];
    const int b = blockIdx.z;
    const int cblk = blockIdx.y * 32, nblk = blockIdx.x * 32;
    const int tx = threadIdx.x, ty = threadIdx.y;     // (32, 8)
    const float* src = features + ((size_t)b * NCH + cblk) * NSUP + nblk;
    #pragma unroll
    for (int r = 0; r < 4; ++r)
        tile[ty + r * 8][tx] = src[(size_t)(ty + r * 8) * NSUP + tx];
    __syncthreads();
    float* dst = feat_t + ((size_t)b * NSUP + nblk) * NCH + cblk;
    #pragma unroll
    for (int r = 0; r < 4; ++r)
        dst[(size_t)(ty + r * 8) * NCH + tx] = tile[tx][ty + r * 8];
}

// ---------- main: 2 queries per block (one wave each) ----------
__global__ __launch_bounds__(128) void mqag_grid(
    const float* __restrict__ query_xyz, const float* __restrict__ support_xyz,
    const void* __restrict__ query_mask, const void* __restrict__ support_mask,
    const float* __restrict__ features, const float* __restrict__ feat_t,
    const float4* __restrict__ pts, const int* __restrict__ starts,
    float* __restrict__ out, int B)
{
#pragma clang fp contract(off)
    const int wib  = threadIdx.x >> 6;           // 0..1
    const int lane = threadIdx.x & 63;
    const int qid  = blockIdx.x * 2 + wib;
    const int b    = qid / NPOINT;
    const int p    = qid % NPOINT;

    __shared__ float buf_all[2][NS * 65];        // transpose bounce, pad 65
    __shared__ int hits_all[2][64];
    __shared__ int slots_all[2][NS];
    float* buf  = buf_all[wib];
    int* hits   = hits_all[wib];
    int* slots  = slots_all[wib];

    const bool m4s = probe_mask4(support_mask);
    const bool m4q = probe_mask4(query_mask);

    const float* sx = support_xyz + (size_t)b * 3 * NSUP;
    const float* sy = sx + NSUP;
    const float* sz = sx + 2 * NSUP;

    const float qx = query_xyz[(size_t)b * 3 * NPOINT + p];
    const float qy = query_xyz[(size_t)b * 3 * NPOINT + NPOINT + p];
    const float qz = query_xyz[(size_t)b * 3 * NPOINT + 2 * NPOINT + p];
    const bool  qm = read_mask(query_mask, b * NPOINT + p, m4q);
    const float qq = (qx * qx + qy * qy) + qz * qz;   // no fma (matches ref)

    int cnt = 0;
    if (qm) {
        const int x0 = max(0, (int)floorf((qx - 0.101f) * 10.f));
        const int x1 = min(GRID1 - 1, (int)floorf((qx + 0.101f) * 10.f));
        const int y0 = max(0, (int)floorf((qy - 0.101f) * 10.f));
        const int y1 = min(GRID1 - 1, (int)floorf((qy + 0.101f) * 10.f));
        const int z0 = max(0, (int)floorf((qz - 0.101f) * 10.f));
        const int z1 = min(GRID1 - 1, (int)floorf((qz + 0.101f) * 10.f));
        const int ncx = x1 - x0 + 1;

        const int*    stb  = starts + b * (CELLS + 1);
        const float4* ptsb = pts + (size_t)b * NSUP;

        // x-consecutive cells -> contiguous pts range (R6-verified).
        for (int cz = z0; cz <= z1; ++cz) {
            for (int cy = y0; cy <= y1; ++cy) {
                const int c0 = x0 + GRID1 * cy + GRID1 * GRID1 * cz;
                const int s0 = stb[c0];
                const int e0 = stb[c0 + ncx];
                for (int tb = s0; tb < e0; tb += 64) {
                    const int g  = tb + lane;
                    const bool valid = g < e0;
                    const float4 pv = ptsb[valid ? g : (e0 - 1)];
                    const int nidx = __float_as_int(pv.w);
                    // EXACT R4 membership arithmetic (bit-exact vs ref):
                    const float ss  = (pv.x * pv.x + pv.y * pv.y) + pv.z * pv.z;
                    const float dot = __builtin_fmaf(qz, pv.z,
                                      __builtin_fmaf(qy, pv.y, qx * pv.x));
                    const float d2  = (qq + ss) - 2.0f * dot;
                    const bool within = valid && (d2 <= 0.01f)
                        && read_mask(support_mask, b * NSUP + nidx, m4s);
                    const unsigned long long bal = __ballot(within);
                    if (within) {
                        const int r = cnt + __popcll(bal & ((1ull << lane) - 1ull));
                        if (r < 64) hits[r] = nidx;
                    }
                    cnt += __popcll(bal);
                }
            }
        }
    }

    __syncthreads();

    if (cnt > 64) {
        // rare overflow: exact ordered linear rescan (R4-verified loop)
        int c2 = 0;
        for (int basei = 0; basei < NSUP; basei += 64) {
            const int n = basei + lane;
            const float x = sx[n], y = sy[n], z = sz[n];
            const bool  m = read_mask(support_mask, b * NSUP + n, m4s);
            const float ss  = (x * x + y * y) + z * z;
            const float dot = __builtin_fmaf(qz, z,
                              __builtin_fmaf(qy, y, qx * x));
            const float d2  = (qq + ss) - 2.0f * dot;
            const bool within = (d2 <= 0.01f) && m;
            const unsigned long long bal = __ballot(within);
            if (within) {
                const int r = c2 + __popcll(bal & ((1ull << lane) - 1ull));
                if (r < NS) slots[r] = n;
            }
            c2 += __popcll(bal);
            if (c2 >= NS) break;
        }
        cnt = c2;
    } else {
        // bitonic sort, 64 lanes ascending (R6-verified); empties = INT_MAX
        int v = (lane < cnt) ? hits[lane] : 0x7FFFFFFF;
        #pragma unroll
        for (int k = 2; k <= 64; k <<= 1) {
            #pragma unroll
            for (int j = k >> 1; j > 0; j >>= 1) {
                const int pv = __shfl_xor(v, j, 64);
                const bool keep_min = ((lane & j) == 0) == ((lane & k) == 0);
                const int mn = min(v, pv), mx = max(v, pv);
                v = keep_min ? mn : mx;
            }
        }
        if (lane < NS && lane < cnt) slots[lane] = v;
    }
    const int found = (cnt < NS) ? cnt : NS;

    __syncthreads();
    const int first = (found > 0) ? slots[0] : 0;
    if (lane < NS && lane >= found) slots[lane] = first;
    __syncthreads();

    // idx_mask (f32 0/1) after new_features
    const size_t nf_elems = (size_t)B * 67 * NPOINT * NS;
    if (lane < NS) {
        out[nf_elems + ((size_t)b * NPOINT + p) * NS + lane] =
            (lane < found) ? 1.0f : 0.0f;
    }

    // xyz channels (ch 0..2): 96 elements, small
    for (int i = 0; i < 2; ++i) {
        const int flat = i * 64 + lane;
        if (flat < 3 * NS) {
            const int ch = flat >> 5;
            const int k  = flat & 31;
            const int idx = slots[k];
            const float s = sx[(size_t)ch * NSUP + idx];
            const float q = (ch == 0) ? qx : ((ch == 1) ? qy : qz);
            out[(((size_t)b * 67 + ch) * NPOINT + p) * NS + k] = (s - q) / 0.1f;
        }
    }

    float* outf = out + (((size_t)b * 67 + 3) * NPOINT) * NS;  // feature chans
    if (feat_t) {
        // dense path: one neighbor's 64 channels = contiguous 256B (lane=ch)
        const int myidx = (lane < NS) ? slots[lane] : 0;
        const float* ftb = feat_t + (size_t)b * NSUP * NCH;
        #pragma unroll 8
        for (int k = 0; k < NS; ++k) {
            const int idx = __shfl(myidx, k, 64);
            buf[k * 65 + lane] = ftb[(size_t)idx * NCH + lane];
        }
        // per-wave RAW on buf -> compiler inserts lgkmcnt waits (no barrier:
        // buf is wave-private)
        for (int i = 0; i < 32; ++i) {
            const int flat = i * 64 + lane;
            const int ch = flat >> 5;          // 0..63
            const int k  = flat & 31;
            outf[(size_t)ch * NPOINT * NS + (size_t)p * NS + k] =
                buf[k * 65 + ch];              // banks (k+ch)%32: 2-way, free
        }
    } else {
        // fallback: R6 gather (column-major features)
        const float* feat = features + (size_t)b * NCH * NSUP;
        for (int i = 0; i < 32; ++i) {
            const int flat = i * 64 + lane;
            const int ch = flat >> 5;
            const int k  = flat & 31;
            const int idx = slots[k];
            outf[(size_t)ch * NPOINT * NS + (size_t)p * NS + k] =
                feat[(size_t)ch * NSUP + idx];
        }
    }
}

// ---------- proven R4 linear kernel (fallback if ws tiny) ----------
__global__ __launch_bounds__(256) void mqag_linear(
    const float* __restrict__ query_xyz, const float* __restrict__ support_xyz,
    const void* __restrict__ query_mask_raw, const void* __restrict__ support_mask_raw,
    const float* __restrict__ features, float* __restrict__ out, int B)
{
#pragma clang fp contract(off)
    const int wib  = threadIdx.x >> 6;
    const int lane = threadIdx.x & 63;
    const int qid  = blockIdx.x * 4 + wib;
    const int b    = qid / NPOINT;
    const int p    = qid % NPOINT;

    __shared__ int slots_all[4][NS];
    int* slots = slots_all[wib];

    const bool m4s = probe_mask4(support_mask_raw);
    const bool m4q = probe_mask4(query_mask_raw);

    const float* sx = support_xyz + (size_t)b * 3 * NSUP;
    const float* sy = sx + NSUP;
    const float* sz = sx + 2 * NSUP;

    const float qx = query_xyz[(size_t)b * 3 * NPOINT + p];
    const float qy = query_xyz[(size_t)b * 3 * NPOINT + NPOINT + p];
    const float qz = query_xyz[(size_t)b * 3 * NPOINT + 2 * NPOINT + p];
    const bool  qm = read_mask(query_mask_raw, b * NPOINT + p, m4q);
    const float qq = (qx * qx + qy * qy) + qz * qz;

    int cnt = 0;
    if (qm) {
        for (int base = 0; base < NSUP; base += 64) {
            const int n = base + lane;
            const float x = sx[n], y = sy[n], z = sz[n];
            const bool  m = read_mask(support_mask_raw, b * NSUP + n, m4s);
            const float ss  = (x * x + y * y) + z * z;
            const float dot = __builtin_fmaf(qz, z, __builtin_fmaf(qy, y, qx * x));
            const float d2  = (qq + ss) - 2.0f * dot;
            const bool within = (d2 <= 0.01f) && m;
            const unsigned long long bal = __ballot(within);
            if (within) {
                const int r = cnt + __popcll(bal & ((1ull << lane) - 1ull));
                if (r < NS) slots[r] = n;
            }
            cnt += __popcll(bal);
            if (cnt >= NS) break;
        }
    }
    const int found = cnt < NS ? cnt : NS;
    __syncthreads();
    const int first = (found > 0) ? slots[0] : 0;
    if (lane < NS && lane >= found) slots[lane] = first;
    __syncthreads();

    const size_t nf_elems = (size_t)B * 67 * NPOINT * NS;
    if (lane < NS) {
        out[nf_elems + ((size_t)b * NPOINT + p) * NS + lane] =
            (lane < found) ? 1.0f : 0.0f;
    }
    const float* feat = features + (size_t)b * NCH * NSUP;
    for (int i = 0; i < (67 * NS + 63) / 64; ++i) {
        const int flat = i * 64 + lane;
        if (flat < 67 * NS) {
            const int ch = flat >> 5;
            const int k  = flat & 31;
            const int idx = slots[k];
            float val;
            if (ch < 3) {
                const float s = sx[(size_t)ch * NSUP + idx];
                const float q = (ch == 0) ? qx : ((ch == 1) ? qy : qz);
                val = (s - q) / 0.1f;
            } else {
                val = feat[(size_t)(ch - 3) * NSUP + idx];
            }
            out[(((size_t)b * 67 + ch) * NPOINT + p) * NS + k] = val;
        }
    }
}

extern "C" void kernel_launch(void* const* d_in, const int* in_sizes, int n_in,
                              void* d_out, int out_size, void* d_ws, size_t ws_size,
                              hipStream_t stream) {
    const float* query_xyz    = (const float*)d_in[0];
    const float* support_xyz  = (const float*)d_in[1];
    const void*  query_mask   = d_in[2];
    const void*  support_mask = d_in[3];
    const float* features     = (const float*)d_in[4];

    const int B = in_sizes[0] / (3 * NPOINT);      // = 4

    // ws layout: pts | starts | cursors | (pad to 256) | feat_t
    const size_t off_pts     = 0;
    const size_t off_starts  = off_pts + (size_t)B * NSUP * sizeof(float4);
    const size_t off_cursors = off_starts + (size_t)B * (CELLS + 1) * sizeof(int);
    size_t off_featt         = off_cursors + (size_t)B * CELLS * sizeof(int);
    off_featt = (off_featt + 255) & ~(size_t)255;
    const size_t need_min  = off_featt;
    const size_t need_full = off_featt + (size_t)B * NSUP * NCH * sizeof(float);

    if (ws_size >= need_min) {
        float4* pts   = (float4*)((char*)d_ws + off_pts);
        int* starts   = (int*)((char*)d_ws + off_starts);
        int* cursors  = (int*)((char*)d_ws + off_cursors);
        float* feat_t = (ws_size >= need_full)
                      ? (float*)((char*)d_ws + off_featt) : nullptr;

        const int nzero = B * (CELLS + 1) + B * CELLS;   // starts+cursors contig
        hipLaunchKernelGGL(zero_ws, dim3((nzero + 255) / 256), dim3(256), 0,
                           stream, starts, nzero);
        hipLaunchKernelGGL(grid_hist, dim3(B * NSUP / 256), dim3(256), 0,
                           stream, support_xyz, support_mask, starts);
        hipLaunchKernelGGL(grid_scan, dim3(B), dim3(1024), 0, stream, starts);
        hipLaunchKernelGGL(grid_fill, dim3(B * NSUP / 256), dim3(256), 0,
                           stream, support_xyz, support_mask, starts, cursors, pts);
        if (feat_t) {
            hipLaunchKernelGGL(transpose_feat,
                               dim3(NSUP / 32, NCH / 32, B), dim3(32, 8), 0,
                               stream, features, feat_t);
        }
        hipLaunchKernelGGL(mqag_grid, dim3(B * NPOINT / 2), dim3(128), 0,
                           stream, query_xyz, support_xyz, query_mask,
                           support_mask, features, feat_t, pts, starts,
                           (float*)d_out, B);
    } else {
        hipLaunchKernelGGL(mqag_linear, dim3(B * NPOINT / 4), dim3(256), 0,
                           stream, query_xyz, support_xyz, query_mask,
                           support_mask, features, (float*)d_out, B);
    }
}

// Round 8
// 122.371 us; speedup vs baseline: 1.5464x; 1.0552x over previous
//
#include <hip/hip_runtime.h>

// MaskedQueryAndGroup — masked ordered ball query + grouping.
// Shapes: B=4, NPOINT=2048, N=8192, C=64, NSAMPLE=32, R=0.1.
//
// Evidence log:
//  R1-R3: fp32 dataset; masks readable as int32; out = new_features
//    (B,67,NPOINT,32) ++ idx_mask (B,NPOINT,32), both f32.
//  R4 PASSED absmax 0.0: dot = fma(qz,z,fma(qy,y,qx*x)), ss/qq plain mul+add,
//    d2=(qq+ss)-2*dot, contract off. DO NOT change d2 arithmetic.
//  R5 FAILED: shfl_up+binary-search load balancer lost candidates. Avoid.
//  R6 PASSED 159.5: grid + x-run enumeration + bitonic sort all verified.
//  R7 PASSED 129.1: parallel build + feat transpose + LDS-bounce gather.
//    Harness fixed cost ~58 us/bench (ws 272MB + out 70MB 0xAA poison fills;
//    R4/R6/R7 all consistent). Kernel budget in R7 ~71 us; transpose alone
//    moves 128 MB (~22 us).
//  R8: kill the transpose. One feature row (b,ch) = 32 KB -> fits LDS.
//    gather_feat: block per (b,ch,chunk): coalesced row load to LDS, gather
//    row[idx] from LDS (random ~4-way conflicts = 1.58x, trivial), float4
//    coalesced stores. HBM: 8 MB feat reads total vs 128 MB transpose.
//    Query kernel writes padded idx to ws (1 MB) + xyz chans + idx_mask.

#define NPOINT 2048
#define NSUP   8192
#define NCH    64
#define NS     32
#define GRID1  10
#define CELLS  1000   // 10*10*10
#define QCHUNK 1024   // queries per gather block

// ---------- helpers ----------
__device__ __forceinline__ bool probe_mask4(const void* mask) {
    // int32/f32 masks have byte 4i+1 == 0 always; byte bools ~90% nonzero.
    const unsigned char* mb = (const unsigned char*)mask;
    const int lane = threadIdx.x & 63;
    return __ballot(mb[4 * lane + 1] != 0) == 0ull;
}
__device__ __forceinline__ bool read_mask(const void* mask, int i, bool is4) {
    return is4 ? (((const int*)mask)[i] != 0)
               : (((const unsigned char*)mask)[i] != 0);
}
__device__ __forceinline__ int cell_of(float x, float y, float z) {
    const int cx = min(GRID1 - 1, (int)(x * 10.0f));
    const int cy = min(GRID1 - 1, (int)(y * 10.0f));
    const int cz = min(GRID1 - 1, (int)(z * 10.0f));
    return cx + GRID1 * cy + GRID1 * GRID1 * cz;
}

// ---------- build step 1: zero starts+cursors ----------
__global__ __launch_bounds__(256) void zero_ws(int* __restrict__ ptr, int n) {
    const int i = blockIdx.x * 256 + threadIdx.x;
    if (i < n) ptr[i] = 0;
}

// ---------- build step 2: histogram (counts at starts[b][cell+1]) ----------
__global__ __launch_bounds__(256) void grid_hist(
    const float* __restrict__ support_xyz, const void* __restrict__ support_mask,
    int* __restrict__ starts)
{
    const bool m4 = probe_mask4(support_mask);
    const int gid = blockIdx.x * 256 + threadIdx.x;   // grid sized B*NSUP exactly
    const int b = gid / NSUP, n = gid % NSUP;
    if (!read_mask(support_mask, gid, m4)) return;
    const float* sx = support_xyz + (size_t)b * 3 * NSUP;
    const int cid = cell_of(sx[n], sx[NSUP + n], sx[2 * NSUP + n]);
    atomicAdd(&starts[b * (CELLS + 1) + cid + 1], 1);
}

// ---------- build step 3: scan (R6-verified Hillis-Steele) ----------
__global__ __launch_bounds__(1024) void grid_scan(int* __restrict__ starts) {
    __shared__ int scanb[1024];
    const int tid = threadIdx.x;
    int* sb = starts + blockIdx.x * (CELLS + 1);
    scanb[tid] = (tid < CELLS) ? sb[tid + 1] : 0;
    __syncthreads();
    for (int d = 1; d < 1024; d <<= 1) {
        int v = 0;
        if (tid >= d) v = scanb[tid - d];
        __syncthreads();
        if (tid >= d) scanb[tid] += v;
        __syncthreads();
    }
    if (tid < CELLS) sb[tid + 1] = scanb[tid];   // sb[0] stays 0 (zero_ws)
}

// ---------- build step 4: fill pts ----------
__global__ __launch_bounds__(256) void grid_fill(
    const float* __restrict__ support_xyz, const void* __restrict__ support_mask,
    const int* __restrict__ starts, int* __restrict__ cursors,
    float4* __restrict__ pts)
{
    const bool m4 = probe_mask4(support_mask);
    const int gid = blockIdx.x * 256 + threadIdx.x;
    const int b = gid / NSUP, n = gid % NSUP;
    if (!read_mask(support_mask, gid, m4)) return;
    const float* sx = support_xyz + (size_t)b * 3 * NSUP;
    const float x = sx[n], y = sx[NSUP + n], z = sx[2 * NSUP + n];
    const int cid = cell_of(x, y, z);
    const int pos = starts[b * (CELLS + 1) + cid]
                  + atomicAdd(&cursors[b * CELLS + cid], 1);
    pts[(size_t)b * NSUP + pos] = make_float4(x, y, z, __int_as_float(n));
}

// ---------- query: scan + sort + idx/xyz/idx_mask (4 queries/block) ----------
__global__ __launch_bounds__(256) void mqag_query(
    const float* __restrict__ query_xyz, const float* __restrict__ support_xyz,
    const void* __restrict__ query_mask, const void* __restrict__ support_mask,
    const float4* __restrict__ pts, const int* __restrict__ starts,
    int* __restrict__ idx_ws, float* __restrict__ out, int B)
{
#pragma clang fp contract(off)
    const int wib  = threadIdx.x >> 6;
    const int lane = threadIdx.x & 63;
    const int qid  = blockIdx.x * 4 + wib;
    const int b    = qid / NPOINT;
    const int p    = qid % NPOINT;

    __shared__ int hits_all[4][64];
    __shared__ int slots_all[4][NS];
    int* hits  = hits_all[wib];
    int* slots = slots_all[wib];

    const bool m4s = probe_mask4(support_mask);
    const bool m4q = probe_mask4(query_mask);

    const float* sx = support_xyz + (size_t)b * 3 * NSUP;
    const float* sy = sx + NSUP;
    const float* sz = sx + 2 * NSUP;

    const float qx = query_xyz[(size_t)b * 3 * NPOINT + p];
    const float qy = query_xyz[(size_t)b * 3 * NPOINT + NPOINT + p];
    const float qz = query_xyz[(size_t)b * 3 * NPOINT + 2 * NPOINT + p];
    const bool  qm = read_mask(query_mask, b * NPOINT + p, m4q);
    const float qq = (qx * qx + qy * qy) + qz * qz;   // no fma (matches ref)

    int cnt = 0;
    if (qm) {
        const int x0 = max(0, (int)floorf((qx - 0.101f) * 10.f));
        const int x1 = min(GRID1 - 1, (int)floorf((qx + 0.101f) * 10.f));
        const int y0 = max(0, (int)floorf((qy - 0.101f) * 10.f));
        const int y1 = min(GRID1 - 1, (int)floorf((qy + 0.101f) * 10.f));
        const int z0 = max(0, (int)floorf((qz - 0.101f) * 10.f));
        const int z1 = min(GRID1 - 1, (int)floorf((qz + 0.101f) * 10.f));
        const int ncx = x1 - x0 + 1;

        const int*    stb  = starts + b * (CELLS + 1);
        const float4* ptsb = pts + (size_t)b * NSUP;

        // x-consecutive cells -> contiguous pts range (R6-verified).
        for (int cz = z0; cz <= z1; ++cz) {
            for (int cy = y0; cy <= y1; ++cy) {
                const int c0 = x0 + GRID1 * cy + GRID1 * GRID1 * cz;
                const int s0 = stb[c0];
                const int e0 = stb[c0 + ncx];
                for (int tb = s0; tb < e0; tb += 64) {
                    const int g  = tb + lane;
                    const bool valid = g < e0;
                    const float4 pv = ptsb[valid ? g : (e0 - 1)];
                    const int nidx = __float_as_int(pv.w);
                    // EXACT R4 membership arithmetic (bit-exact vs ref):
                    const float ss  = (pv.x * pv.x + pv.y * pv.y) + pv.z * pv.z;
                    const float dot = __builtin_fmaf(qz, pv.z,
                                      __builtin_fmaf(qy, pv.y, qx * pv.x));
                    const float d2  = (qq + ss) - 2.0f * dot;
                    const bool within = valid && (d2 <= 0.01f)
                        && read_mask(support_mask, b * NSUP + nidx, m4s);
                    const unsigned long long bal = __ballot(within);
                    if (within) {
                        const int r = cnt + __popcll(bal & ((1ull << lane) - 1ull));
                        if (r < 64) hits[r] = nidx;
                    }
                    cnt += __popcll(bal);
                }
            }
        }
    }

    __syncthreads();

    if (cnt > 64) {
        // rare overflow: exact ordered linear rescan (R4-verified loop)
        int c2 = 0;
        for (int basei = 0; basei < NSUP; basei += 64) {
            const int n = basei + lane;
            const float x = sx[n], y = sy[n], z = sz[n];
            const bool  m = read_mask(support_mask, b * NSUP + n, m4s);
            const float ss  = (x * x + y * y) + z * z;
            const float dot = __builtin_fmaf(qz, z,
                              __builtin_fmaf(qy, y, qx * x));
            const float d2  = (qq + ss) - 2.0f * dot;
            const bool within = (d2 <= 0.01f) && m;
            const unsigned long long bal = __ballot(within);
            if (within) {
                const int r = c2 + __popcll(bal & ((1ull << lane) - 1ull));
                if (r < NS) slots[r] = n;
            }
            c2 += __popcll(bal);
            if (c2 >= NS) break;
        }
        cnt = c2;
    } else {
        // bitonic sort, 64 lanes ascending (R6-verified); empties = INT_MAX
        int v = (lane < cnt) ? hits[lane] : 0x7FFFFFFF;
        #pragma unroll
        for (int k = 2; k <= 64; k <<= 1) {
            #pragma unroll
            for (int j = k >> 1; j > 0; j >>= 1) {
                const int pv = __shfl_xor(v, j, 64);
                const bool keep_min = ((lane & j) == 0) == ((lane & k) == 0);
                const int mn = min(v, pv), mx = max(v, pv);
                v = keep_min ? mn : mx;
            }
        }
        if (lane < NS && lane < cnt) slots[lane] = v;
    }
    const int found = (cnt < NS) ? cnt : NS;

    __syncthreads();
    const int first = (found > 0) ? slots[0] : 0;
    if (lane < NS && lane >= found) slots[lane] = first;
    __syncthreads();

    // padded idx -> ws (consumed by gather_feat)
    if (lane < NS) idx_ws[((size_t)b * NPOINT + p) * NS + lane] = slots[lane];

    // idx_mask (f32 0/1) after new_features
    const size_t nf_elems = (size_t)B * 67 * NPOINT * NS;
    if (lane < NS) {
        out[nf_elems + ((size_t)b * NPOINT + p) * NS + lane] =
            (lane < found) ? 1.0f : 0.0f;
    }

    // xyz channels (ch 0..2): 96 elements per query
    for (int i = 0; i < 2; ++i) {
        const int flat = i * 64 + lane;
        if (flat < 3 * NS) {
            const int ch = flat >> 5;
            const int k  = flat & 31;
            const int idx = slots[k];
            const float s = sx[(size_t)ch * NSUP + idx];
            const float q = (ch == 0) ? qx : ((ch == 1) ? qy : qz);
            out[(((size_t)b * 67 + ch) * NPOINT + p) * NS + k] = (s - q) / 0.1f;
        }
    }
}

// ---------- gather: one (b,ch) feature row in LDS, coalesced in/out ----------
__global__ __launch_bounds__(256) void gather_feat(
    const float* __restrict__ features, const int* __restrict__ idx_ws,
    float* __restrict__ out, int B)
{
    __shared__ float row[NSUP];                       // 32 KB
    const int bc = blockIdx.y;                        // b*NCH + ch
    const int b  = bc / NCH, ch = bc % NCH;
    const int p0 = blockIdx.x * QCHUNK;

    const float* src = features + ((size_t)b * NCH + ch) * NSUP;
    const float4* src4 = (const float4*)src;
    for (int i = threadIdx.x; i < NSUP / 4; i += 256)
        ((float4*)row)[i] = src4[i];
    __syncthreads();

    const int4* idx4 = (const int4*)(idx_ws + ((size_t)b * NPOINT + p0) * NS);
    float4* dst4 = (float4*)(out + (((size_t)b * 67 + 3 + ch) * NPOINT + p0) * NS);
    for (int e = threadIdx.x; e < QCHUNK * NS / 4; e += 256) {
        const int4 iv = idx4[e];
        dst4[e] = make_float4(row[iv.x], row[iv.y], row[iv.z], row[iv.w]);
    }
}

// ---------- proven R4 linear kernel (fallback if ws tiny) ----------
__global__ __launch_bounds__(256) void mqag_linear(
    const float* __restrict__ query_xyz, const float* __restrict__ support_xyz,
    const void* __restrict__ query_mask_raw, const void* __restrict__ support_mask_raw,
    const float* __restrict__ features, float* __restrict__ out, int B)
{
#pragma clang fp contract(off)
    const int wib  = threadIdx.x >> 6;
    const int lane = threadIdx.x & 63;
    const int qid  = blockIdx.x * 4 + wib;
    const int b    = qid / NPOINT;
    const int p    = qid % NPOINT;

    __shared__ int slots_all[4][NS];
    int* slots = slots_all[wib];

    const bool m4s = probe_mask4(support_mask_raw);
    const bool m4q = probe_mask4(query_mask_raw);

    const float* sx = support_xyz + (size_t)b * 3 * NSUP;
    const float* sy = sx + NSUP;
    const float* sz = sx + 2 * NSUP;

    const float qx = query_xyz[(size_t)b * 3 * NPOINT + p];
    const float qy = query_xyz[(size_t)b * 3 * NPOINT + NPOINT + p];
    const float qz = query_xyz[(size_t)b * 3 * NPOINT + 2 * NPOINT + p];
    const bool  qm = read_mask(query_mask_raw, b * NPOINT + p, m4q);
    const float qq = (qx * qx + qy * qy) + qz * qz;

    int cnt = 0;
    if (qm) {
        for (int base = 0; base < NSUP; base += 64) {
            const int n = base + lane;
            const float x = sx[n], y = sy[n], z = sz[n];
            const bool  m = read_mask(support_mask_raw, b * NSUP + n, m4s);
            const float ss  = (x * x + y * y) + z * z;
            const float dot = __builtin_fmaf(qz, z, __builtin_fmaf(qy, y, qx * x));
            const float d2  = (qq + ss) - 2.0f * dot;
            const bool within = (d2 <= 0.01f) && m;
            const unsigned long long bal = __ballot(within);
            if (within) {
                const int r = cnt + __popcll(bal & ((1ull << lane) - 1ull));
                if (r < NS) slots[r] = n;
            }
            cnt += __popcll(bal);
            if (cnt >= NS) break;
        }
    }
    const int found = cnt < NS ? cnt : NS;
    __syncthreads();
    const int first = (found > 0) ? slots[0] : 0;
    if (lane < NS && lane >= found) slots[lane] = first;
    __syncthreads();

    const size_t nf_elems = (size_t)B * 67 * NPOINT * NS;
    if (lane < NS) {
        out[nf_elems + ((size_t)b * NPOINT + p) * NS + lane] =
            (lane < found) ? 1.0f : 0.0f;
    }
    const float* feat = features + (size_t)b * NCH * NSUP;
    for (int i = 0; i < (67 * NS + 63) / 64; ++i) {
        const int flat = i * 64 + lane;
        if (flat < 67 * NS) {
            const int ch = flat >> 5;
            const int k  = flat & 31;
            const int idx = slots[k];
            float val;
            if (ch < 3) {
                const float s = sx[(size_t)ch * NSUP + idx];
                const float q = (ch == 0) ? qx : ((ch == 1) ? qy : qz);
                val = (s - q) / 0.1f;
            } else {
                val = feat[(size_t)(ch - 3) * NSUP + idx];
            }
            out[(((size_t)b * 67 + ch) * NPOINT + p) * NS + k] = val;
        }
    }
}

extern "C" void kernel_launch(void* const* d_in, const int* in_sizes, int n_in,
                              void* d_out, int out_size, void* d_ws, size_t ws_size,
                              hipStream_t stream) {
    const float* query_xyz    = (const float*)d_in[0];
    const float* support_xyz  = (const float*)d_in[1];
    const void*  query_mask   = d_in[2];
    const void*  support_mask = d_in[3];
    const float* features     = (const float*)d_in[4];

    const int B = in_sizes[0] / (3 * NPOINT);      // = 4

    // ws layout: pts | starts | cursors | idx
    const size_t off_pts     = 0;
    const size_t off_starts  = off_pts + (size_t)B * NSUP * sizeof(float4);
    const size_t off_cursors = off_starts + (size_t)B * (CELLS + 1) * sizeof(int);
    const size_t off_idx     = off_cursors + (size_t)B * CELLS * sizeof(int);
    const size_t need = off_idx + (size_t)B * NPOINT * NS * sizeof(int);

    if (ws_size >= need) {
        float4* pts  = (float4*)((char*)d_ws + off_pts);
        int* starts  = (int*)((char*)d_ws + off_starts);
        int* cursors = (int*)((char*)d_ws + off_cursors);
        int* idx_ws  = (int*)((char*)d_ws + off_idx);

        const int nzero = B * (CELLS + 1) + B * CELLS;   // starts+cursors contig
        hipLaunchKernelGGL(zero_ws, dim3((nzero + 255) / 256), dim3(256), 0,
                           stream, starts, nzero);
        hipLaunchKernelGGL(grid_hist, dim3(B * NSUP / 256), dim3(256), 0,
                           stream, support_xyz, support_mask, starts);
        hipLaunchKernelGGL(grid_scan, dim3(B), dim3(1024), 0, stream, starts);
        hipLaunchKernelGGL(grid_fill, dim3(B * NSUP / 256), dim3(256), 0,
                           stream, support_xyz, support_mask, starts, cursors, pts);
        hipLaunchKernelGGL(mqag_query, dim3(B * NPOINT / 4), dim3(256), 0,
                           stream, query_xyz, support_xyz, query_mask,
                           support_mask, pts, starts, idx_ws, (float*)d_out, B);
        hipLaunchKernelGGL(gather_feat, dim3(NPOINT / QCHUNK, B * NCH), dim3(256),
                           0, stream, features, idx_ws, (float*)d_out, B);
    } else {
        hipLaunchKernelGGL(mqag_linear, dim3(B * NPOINT / 4), dim3(256), 0,
                           stream, query_xyz, support_xyz, query_mask,
                           support_mask, features, (float*)d_out, B);
    }
}